// Round 1
// baseline (1120.960 us; speedup 1.0000x reference)
//
#include <hip/hip_runtime.h>
#include <hip/hip_bf16.h>
#include <math.h>

// Problem constants
#define B 256
#define D 1024
#define H 8
#define HD 128
#define P 2048
#define HID 1024
#define EPS 1e-5f

// d_out layout (floats): out[B*D], c_t[B*H*HD*HD], n_t[B*H*HD], m_t[B*H]
#define C_OFF   262144      // 256*1024
#define N_OFF   33816576    // C_OFF + 256*8*128*128
#define M_OFF   34078720    // N_OFF + 256*8*128

// workspace layout (floats)
#define WS_XN   0
#define WS_XT   262144
#define WS_RT   786432
#define WS_XC   1048576
#define WS_Q    1572864
#define WS_K    1835008
#define WS_V    2097152
#define WS_OT   2359296
#define WS_SKP  2621440
#define WS_IT   2883584
#define WS_FT   2885632
#define WS_Y    2887680

// ---------------------------------------------------------------------------
// LayerNorm: one block per row of seq [B, D]
// ---------------------------------------------------------------------------
__global__ __launch_bounds__(256) void ln_kernel(
    const float* __restrict__ seq, const float* __restrict__ w,
    const float* __restrict__ b, float* __restrict__ xn)
{
    const int row = blockIdx.x;
    const int tid = threadIdx.x;
    const int lane = tid & 63, wv = tid >> 6;
    const float* x = seq + (size_t)row * D;
    __shared__ float red[8];

    float vals[4];
    float s = 0.f, s2 = 0.f;
#pragma unroll
    for (int i = 0; i < 4; ++i) {
        float v = x[tid + 256 * i];
        vals[i] = v; s += v; s2 += v * v;
    }
#pragma unroll
    for (int off = 32; off; off >>= 1) {
        s  += __shfl_down(s, off, 64);
        s2 += __shfl_down(s2, off, 64);
    }
    if (lane == 0) { red[wv] = s; red[4 + wv] = s2; }
    __syncthreads();
    const float tot  = red[0] + red[1] + red[2] + red[3];
    const float tot2 = red[4] + red[5] + red[6] + red[7];
    const float mu = tot * (1.f / D);
    const float var = tot2 * (1.f / D) - mu * mu;
    const float rs = rsqrtf(var + EPS);
#pragma unroll
    for (int i = 0; i < 4; ++i) {
        const int c = tid + 256 * i;
        xn[(size_t)row * D + c] = (vals[i] - mu) * rs * w[c] + b[c];
    }
}

// ---------------------------------------------------------------------------
// Tiled f32 GEMM: C[M,N] = act((A[M,K] @ W[N,K]^T + bias) * scale) + res
// 64x64 tile, 256 threads, 4x4 per thread. ACT: 0=none, 1=sigmoid
// ---------------------------------------------------------------------------
template<int ACT>
__global__ __launch_bounds__(256) void gemm_f32(
    const float* __restrict__ A, const float* __restrict__ W,
    const float* __restrict__ bias, const float* __restrict__ res,
    float* __restrict__ C, int M, int N, int K, float scale)
{
    __shared__ float As[16][68];
    __shared__ float Ws[16][68];
    const int tid = threadIdx.x;
    const int tx = tid & 15, ty = tid >> 4;
    const int n0 = blockIdx.x * 64, m0 = blockIdx.y * 64;
    const int kk = tid & 15, rr = tid >> 4;

    float acc[4][4] = {};

    for (int k0 = 0; k0 < K; k0 += 16) {
#pragma unroll
        for (int i = 0; i < 4; ++i) {
            const int r = rr + i * 16;
            As[kk][r] = A[(size_t)(m0 + r) * K + k0 + kk];
            Ws[kk][r] = W[(size_t)(n0 + r) * K + k0 + kk];
        }
        __syncthreads();
#pragma unroll
        for (int kx = 0; kx < 16; ++kx) {
            const float4 a4 = *(const float4*)&As[kx][ty * 4];
            const float4 w4 = *(const float4*)&Ws[kx][tx * 4];
            const float av[4] = {a4.x, a4.y, a4.z, a4.w};
            const float wvv[4] = {w4.x, w4.y, w4.z, w4.w};
#pragma unroll
            for (int i = 0; i < 4; ++i)
#pragma unroll
                for (int j = 0; j < 4; ++j)
                    acc[i][j] = fmaf(av[i], wvv[j], acc[i][j]);
        }
        __syncthreads();
    }

    float bb[4] = {0.f, 0.f, 0.f, 0.f};
    if (bias) {
        const float4 b4 = *(const float4*)&bias[n0 + tx * 4];
        bb[0] = b4.x; bb[1] = b4.y; bb[2] = b4.z; bb[3] = b4.w;
    }
#pragma unroll
    for (int i = 0; i < 4; ++i) {
        const int m = m0 + ty * 4 + i;
        float vals[4];
#pragma unroll
        for (int j = 0; j < 4; ++j) {
            float v = (acc[i][j] + bb[j]) * scale;
            if (ACT == 1) v = 1.f / (1.f + expf(-v));
            vals[j] = v;
        }
        float4 ov = {vals[0], vals[1], vals[2], vals[3]};
        if (res) {
            const float4 r4 = *(const float4*)&res[(size_t)m * N + n0 + tx * 4];
            ov.x += r4.x; ov.y += r4.y; ov.z += r4.z; ov.w += r4.w;
        }
        *(float4*)&C[(size_t)m * N + n0 + tx * 4] = ov;
    }
}

// ---------------------------------------------------------------------------
// Causal conv (feature axis, K=4) + SiLU: x_t [B,P] -> x_c [B,P]
// ---------------------------------------------------------------------------
__global__ __launch_bounds__(256) void conv_silu_kernel(
    const float* __restrict__ xt, const float* __restrict__ cw,
    const float* __restrict__ cb, float* __restrict__ xc)
{
    const int idx = blockIdx.x * 256 + threadIdx.x;  // B*P threads
    const int b = idx >> 11, i = idx & 2047;
    const float* row = xt + (size_t)b * P;
    float acc = cb[0];
#pragma unroll
    for (int j = 0; j < 4; ++j) {
        const int src = i + j - 3;
        if (src >= 0) acc = fmaf(cw[j], row[src], acc);
    }
    xc[idx] = acc / (1.f + expf(-acc));   // silu
}

// ---------------------------------------------------------------------------
// i_t, f_t: [B,H] = x_c @ Wi/Wf^T + b. One block per (b,h).
// ---------------------------------------------------------------------------
__global__ __launch_bounds__(256) void if_kernel(
    const float* __restrict__ xc,
    const float* __restrict__ Wi, const float* __restrict__ Wib,
    const float* __restrict__ Wf, const float* __restrict__ Wfb,
    float* __restrict__ it, float* __restrict__ ft)
{
    const int blk = blockIdx.x;          // b*H + h
    const int b = blk >> 3, h = blk & 7;
    const int tid = threadIdx.x;
    const int lane = tid & 63, wv = tid >> 6;
    const float* x = xc + (size_t)b * P;
    const float* wi = Wi + (size_t)h * P;
    const float* wf = Wf + (size_t)h * P;
    float pi = 0.f, pf = 0.f;
    for (int p = tid; p < P; p += 256) {
        const float xv = x[p];
        pi = fmaf(xv, wi[p], pi);
        pf = fmaf(xv, wf[p], pf);
    }
    __shared__ float red[8];
#pragma unroll
    for (int off = 32; off; off >>= 1) {
        pi += __shfl_down(pi, off, 64);
        pf += __shfl_down(pf, off, 64);
    }
    if (lane == 0) { red[wv] = pi; red[4 + wv] = pf; }
    __syncthreads();
    if (tid == 0) {
        it[blk] = red[0] + red[1] + red[2] + red[3] + Wib[h];
        ft[blk] = red[4] + red[5] + red[6] + red[7] + Wfb[h];
    }
}

// ---------------------------------------------------------------------------
// Fused gate kernel: one block per (b,h). Computes m_t, i_g, f_g, n_t, den,
// c_t update + num = c_t @ q, then h_t -> GroupNorm -> +skip -> *silu(r_t).
// ---------------------------------------------------------------------------
__global__ __launch_bounds__(256) void gate_kernel(
    const float* __restrict__ c_tm1, const float* __restrict__ n_tm1,
    const float* __restrict__ m_tm1, const float* __restrict__ it_a,
    const float* __restrict__ ft_a, const float* __restrict__ q,
    const float* __restrict__ k, const float* __restrict__ v,
    const float* __restrict__ ot, const float* __restrict__ skp,
    const float* __restrict__ rt, const float* __restrict__ gn_w,
    const float* __restrict__ gn_b, float* __restrict__ c_out,
    float* __restrict__ n_out, float* __restrict__ m_out,
    float* __restrict__ y)
{
    const int blk = blockIdx.x;          // b*H + h
    const int b = blk >> 3, h = blk & 7;
    const int tid = threadIdx.x;
    const int lane = tid & 63, wv = tid >> 6;

    __shared__ float sk_[128], sq_[128], sv_[128], snum[128];
    __shared__ float red[8];

    const float it = it_a[blk], ft = ft_a[blk], mp = m_tm1[blk];
    const float mt = fmaxf(ft + mp, it);
    const float ig = expf(it - mt);
    const float fg = expf(ft - mt + mp);
    if (tid == 0) m_out[blk] = mt;

    const int hid_off = b * HID + h * HD;
    float den_p = 0.f;
    if (tid < 128) {
        const float kd = k[hid_off + tid];
        const float qd = q[hid_off + tid];
        sk_[tid] = kd; sq_[tid] = qd; sv_[tid] = v[hid_off + tid];
        const float nn = fg * n_tm1[(size_t)blk * HD + tid] + ig * kd;
        n_out[(size_t)blk * HD + tid] = nn;
        den_p = nn * qd;
    }
    __syncthreads();
#pragma unroll
    for (int off = 32; off; off >>= 1) den_p += __shfl_down(den_p, off, 64);
    if (lane == 0) red[wv] = den_p;
    __syncthreads();
    const float den = fmaxf(red[0] + red[1] + red[2] + red[3], 1.0f);

    // main 128x128 tile: wave wv handles rows d = 4*r + wv, lane covers p=2l,2l+1
    const float k0 = sk_[2 * lane], k1 = sk_[2 * lane + 1];
    const float q0 = sq_[2 * lane], q1 = sq_[2 * lane + 1];
    const size_t cbase = (size_t)blk * (HD * HD);
#pragma unroll 4
    for (int r = 0; r < 32; ++r) {
        const int d = r * 4 + wv;
        const float2 c2 = *(const float2*)(c_tm1 + cbase + d * HD + 2 * lane);
        const float a = ig * sv_[d];
        const float c0v = fmaf(fg, c2.x, a * k0);
        const float c1v = fmaf(fg, c2.y, a * k1);
        float2 st; st.x = c0v; st.y = c1v;
        *(float2*)(c_out + cbase + d * HD + 2 * lane) = st;
        float psum = c0v * q0 + c1v * q1;
#pragma unroll
        for (int off = 32; off; off >>= 1) psum += __shfl_down(psum, off, 64);
        if (lane == 0) snum[d] = psum;
    }
    __syncthreads();

    // phase 2: h_t, GroupNorm, skip, silu(r_t)
    float hval = 0.f, s1 = 0.f, s2 = 0.f;
    if (tid < 128) {
        hval = ot[hid_off + tid] * snum[tid] / den;
        s1 = hval; s2 = hval * hval;
    }
#pragma unroll
    for (int off = 32; off; off >>= 1) {
        s1 += __shfl_down(s1, off, 64);
        s2 += __shfl_down(s2, off, 64);
    }
    if (lane == 0) { red[wv] = s1; red[4 + wv] = s2; }
    __syncthreads();
    const float mu = (red[0] + red[1] + red[2] + red[3]) * (1.f / HD);
    const float ms = (red[4] + red[5] + red[6] + red[7]) * (1.f / HD);
    const float var = ms - mu * mu;
    if (tid < 128) {
        const float hn = (hval - mu) * rsqrtf(var + EPS) * gn_w[h * HD + tid]
                         + gn_b[h * HD + tid];
        const float sr = rt[hid_off + tid];
        const float silu_r = sr / (1.f + expf(-sr));
        y[hid_off + tid] = (hn + skp[hid_off + tid]) * silu_r;
    }
}

// ---------------------------------------------------------------------------
extern "C" void kernel_launch(void* const* d_in, const int* in_sizes, int n_in,
                              void* d_out, int out_size, void* d_ws, size_t ws_size,
                              hipStream_t stream) {
    const float* seq    = (const float*)d_in[0];
    const float* c_tm1  = (const float*)d_in[1];
    const float* n_tm1  = (const float*)d_in[2];
    const float* m_tm1  = (const float*)d_in[3];
    const float* ln_w   = (const float*)d_in[4];
    const float* ln_b   = (const float*)d_in[5];
    const float* gn_w   = (const float*)d_in[6];
    const float* gn_b   = (const float*)d_in[7];
    const float* up_l_w = (const float*)d_in[8];
    const float* up_l_b = (const float*)d_in[9];
    const float* up_r_w = (const float*)d_in[10];
    const float* up_r_b = (const float*)d_in[11];
    const float* down_w = (const float*)d_in[12];
    const float* down_b = (const float*)d_in[13];
    const float* Wi_w   = (const float*)d_in[14];
    const float* Wi_b   = (const float*)d_in[15];
    const float* Wf_w   = (const float*)d_in[16];
    const float* Wf_b   = (const float*)d_in[17];
    const float* Wo_w   = (const float*)d_in[18];
    const float* Wo_b   = (const float*)d_in[19];
    const float* Wq_w   = (const float*)d_in[20];
    const float* Wq_b   = (const float*)d_in[21];
    const float* Wk_w   = (const float*)d_in[22];
    const float* Wk_b   = (const float*)d_in[23];
    const float* Wv_w   = (const float*)d_in[24];
    const float* Wv_b   = (const float*)d_in[25];
    const float* conv_w = (const float*)d_in[26];
    const float* conv_b = (const float*)d_in[27];
    const float* skip_w = (const float*)d_in[28];

    float* ws = (float*)d_ws;
    float* x_n  = ws + WS_XN;
    float* x_t  = ws + WS_XT;
    float* r_t  = ws + WS_RT;
    float* x_c  = ws + WS_XC;
    float* qb   = ws + WS_Q;
    float* kb   = ws + WS_K;
    float* vb   = ws + WS_V;
    float* otb  = ws + WS_OT;
    float* skpb = ws + WS_SKP;
    float* itb  = ws + WS_IT;
    float* ftb  = ws + WS_FT;
    float* yb   = ws + WS_Y;

    float* out0  = (float*)d_out;
    float* c_out = out0 + C_OFF;
    float* n_out = out0 + N_OFF;
    float* m_out = out0 + M_OFF;

    const float kscale = 0.08838834764831845f;  // 1/sqrt(128)

    ln_kernel<<<B, 256, 0, stream>>>(seq, ln_w, ln_b, x_n);

    gemm_f32<0><<<dim3(P / 64, B / 64), 256, 0, stream>>>(
        x_n, up_l_w, up_l_b, nullptr, x_t, B, P, D, 1.f);
    gemm_f32<0><<<dim3(HID / 64, B / 64), 256, 0, stream>>>(
        x_n, up_r_w, up_r_b, nullptr, r_t, B, HID, D, 1.f);

    conv_silu_kernel<<<(B * P) / 256, 256, 0, stream>>>(x_t, conv_w, conv_b, x_c);

    gemm_f32<0><<<dim3(HID / 64, B / 64), 256, 0, stream>>>(
        x_c, Wq_w, Wq_b, nullptr, qb, B, HID, P, 1.f);
    gemm_f32<0><<<dim3(HID / 64, B / 64), 256, 0, stream>>>(
        x_c, Wk_w, Wk_b, nullptr, kb, B, HID, P, kscale);
    gemm_f32<0><<<dim3(HID / 64, B / 64), 256, 0, stream>>>(
        x_t, Wv_w, Wv_b, nullptr, vb, B, HID, P, 1.f);
    gemm_f32<1><<<dim3(HID / 64, B / 64), 256, 0, stream>>>(
        x_t, Wo_w, Wo_b, nullptr, otb, B, HID, P, 1.f);
    gemm_f32<0><<<dim3(HID / 64, B / 64), 256, 0, stream>>>(
        x_c, skip_w, nullptr, nullptr, skpb, B, HID, P, 1.f);

    if_kernel<<<B * H, 256, 0, stream>>>(x_c, Wi_w, Wi_b, Wf_w, Wf_b, itb, ftb);

    gate_kernel<<<B * H, 256, 0, stream>>>(
        c_tm1, n_tm1, m_tm1, itb, ftb, qb, kb, vb, otb, skpb, r_t,
        gn_w, gn_b, c_out, n_out, m_out, yb);

    gemm_f32<0><<<dim3(D / 64, B / 64), 256, 0, stream>>>(
        yb, down_w, down_b, seq, out0, B, D, HID, 1.f);
}

// Round 3
// 396.680 us; speedup vs baseline: 2.8259x; 2.8259x over previous
//
#include <hip/hip_runtime.h>
#include <hip/hip_bf16.h>
#include <math.h>

#define B 256
#define D 1024
#define H 8
#define HD 128
#define P 2048
#define HID 1024
#define EPS 1e-5f

typedef __hip_bfloat16 bf16;
typedef short short8 __attribute__((ext_vector_type(8)));
typedef float f32x4 __attribute__((ext_vector_type(4)));

#define AS1C(p) ((const __attribute__((address_space(1))) void*)(p))
#define AS3(p)  ((__attribute__((address_space(3))) void*)(p))

// ---------------------------------------------------------------------------
// Zero the split-K f32 accumulators (replaces hipMemsetAsync: no host API
// inside kernel_launch). 2359296 floats = 589824 float4.
// ---------------------------------------------------------------------------
__global__ __launch_bounds__(256) void zero_kernel(float* __restrict__ p) {
    const int i = blockIdx.x * 256 + threadIdx.x;
    ((float4*)p)[i] = float4{0.f, 0.f, 0.f, 0.f};
}

// ---------------------------------------------------------------------------
// Weight conversion f32 -> bf16 (8 segments, 4 elems/thread)
// ---------------------------------------------------------------------------
struct CvtSegs { const float* src[8]; bf16* dst[8]; };

__global__ __launch_bounds__(256) void convert_kernel(CvtSegs cs) {
    const int idx = blockIdx.x * 256 + threadIdx.x;   // 4-elem chunk id
    const float* src; bf16* dst; int base;
    if      (idx <  524288) { src = cs.src[0]; dst = cs.dst[0]; base = 0; }
    else if (idx <  786432) { src = cs.src[1]; dst = cs.dst[1]; base = 524288; }
    else if (idx < 1310720) { src = cs.src[2]; dst = cs.dst[2]; base = 786432; }
    else if (idx < 1835008) { src = cs.src[3]; dst = cs.dst[3]; base = 1310720; }
    else if (idx < 2359296) { src = cs.src[4]; dst = cs.dst[4]; base = 1835008; }
    else if (idx < 2883584) { src = cs.src[5]; dst = cs.dst[5]; base = 2359296; }
    else if (idx < 3407872) { src = cs.src[6]; dst = cs.dst[6]; base = 2883584; }
    else                    { src = cs.src[7]; dst = cs.dst[7]; base = 3407872; }
    const int j = idx - base;
    const float4 v = ((const float4*)src)[j];
    union { bf16 h[4]; uint2 u; } tmp;
    tmp.h[0] = __float2bfloat16(v.x); tmp.h[1] = __float2bfloat16(v.y);
    tmp.h[2] = __float2bfloat16(v.z); tmp.h[3] = __float2bfloat16(v.w);
    *(uint2*)&dst[4 * j] = tmp.u;
}

// ---------------------------------------------------------------------------
// LayerNorm -> bf16 output
// ---------------------------------------------------------------------------
__global__ __launch_bounds__(256) void ln_kernel(
    const float* __restrict__ seq, const float* __restrict__ w,
    const float* __restrict__ b, bf16* __restrict__ xn)
{
    const int row = blockIdx.x;
    const int tid = threadIdx.x;
    const int lane = tid & 63, wv = tid >> 6;
    const float* x = seq + (size_t)row * D;
    __shared__ float red[8];

    float vals[4];
    float s = 0.f, s2 = 0.f;
#pragma unroll
    for (int i = 0; i < 4; ++i) {
        float v = x[tid + 256 * i];
        vals[i] = v; s += v; s2 += v * v;
    }
#pragma unroll
    for (int off = 32; off; off >>= 1) {
        s  += __shfl_down(s, off, 64);
        s2 += __shfl_down(s2, off, 64);
    }
    if (lane == 0) { red[wv] = s; red[4 + wv] = s2; }
    __syncthreads();
    const float tot  = red[0] + red[1] + red[2] + red[3];
    const float tot2 = red[4] + red[5] + red[6] + red[7];
    const float mu = tot * (1.f / D);
    const float var = tot2 * (1.f / D) - mu * mu;
    const float rs = rsqrtf(var + EPS);
#pragma unroll
    for (int i = 0; i < 4; ++i) {
        const int c = tid + 256 * i;
        xn[(size_t)row * D + c] = __float2bfloat16((vals[i] - mu) * rs * w[c] + b[c]);
    }
}

// ---------------------------------------------------------------------------
// bf16 MFMA GEMM, split-K, atomicAdd f32 epilogue.
// Tile 64x64, BK=32, 4 waves (each 32x32 via 2x2 of 16x16x32 MFMA).
// Segments of 16 N-tiles each select A/W/O pointers per block.
// ---------------------------------------------------------------------------
struct Segs {
    const bf16* A[5];
    const bf16* W[5];
    float* O[5];
    int ostride[5];
};

__global__ __launch_bounds__(256) void gemm_bf16_sk(Segs segs, int K, int KS) {
    const int nt = blockIdx.x;
    const int seg = nt >> 4, nloc = nt & 15;
    const int m0 = blockIdx.y * 64;
    const int k0 = blockIdx.z * KS;
    const bf16* Ab = segs.A[seg];
    const bf16* Wb = segs.W[seg] + (size_t)(nloc * 64) * K;

    __shared__ bf16 As[2][64 * 32];
    __shared__ bf16 Bs[2][64 * 32];

    const int tid = threadIdx.x;
    const int srow = tid >> 2, scol = (tid & 3) * 8;
    const bf16* gA = Ab + (size_t)(m0 + srow) * K + k0 + scol;
    const bf16* gB = Wb + (size_t)srow * K + k0 + scol;

    const int lane = tid & 63, wave = tid >> 6;
    const int wm = (wave >> 1) * 32, wn = (wave & 1) * 32;
    const int fr = lane & 15, fk = (lane >> 4) * 8;
    const int aoff = (wm + fr) * 32 + fk;
    const int boff = (wn + fr) * 32 + fk;

    f32x4 acc00 = {0.f, 0.f, 0.f, 0.f};
    f32x4 acc01 = {0.f, 0.f, 0.f, 0.f};
    f32x4 acc10 = {0.f, 0.f, 0.f, 0.f};
    f32x4 acc11 = {0.f, 0.f, 0.f, 0.f};

    const int nIter = KS >> 5;

    // prologue: stage iter 0 into buf 0
    __builtin_amdgcn_global_load_lds(AS1C(gA), AS3(&As[0][tid * 8]), 16, 0, 0);
    __builtin_amdgcn_global_load_lds(AS1C(gB), AS3(&Bs[0][tid * 8]), 16, 0, 0);

    int buf = 0;
    for (int it = 0; it < nIter; ++it) {
        __syncthreads();   // drains vmcnt -> buf ready; prev readers of buf^1 done
        if (it + 1 < nIter) {
            const int ko = (it + 1) * 32;
            __builtin_amdgcn_global_load_lds(AS1C(gA + ko), AS3(&As[buf ^ 1][tid * 8]), 16, 0, 0);
            __builtin_amdgcn_global_load_lds(AS1C(gB + ko), AS3(&Bs[buf ^ 1][tid * 8]), 16, 0, 0);
        }
        const short8 a0 = *(const short8*)&As[buf][aoff];
        const short8 a1 = *(const short8*)&As[buf][aoff + 512];
        const short8 b0 = *(const short8*)&Bs[buf][boff];
        const short8 b1 = *(const short8*)&Bs[buf][boff + 512];
        acc00 = __builtin_amdgcn_mfma_f32_16x16x32_bf16(a0, b0, acc00, 0, 0, 0);
        acc01 = __builtin_amdgcn_mfma_f32_16x16x32_bf16(a0, b1, acc01, 0, 0, 0);
        acc10 = __builtin_amdgcn_mfma_f32_16x16x32_bf16(a1, b0, acc10, 0, 0, 0);
        acc11 = __builtin_amdgcn_mfma_f32_16x16x32_bf16(a1, b1, acc11, 0, 0, 0);
        buf ^= 1;
    }

    float* Ob = segs.O[seg] + nloc * 64 + wn;
    const int ost = segs.ostride[seg];
    const int r0 = m0 + wm + (lane >> 4) * 4;
    const int c0 = lane & 15;
#pragma unroll
    for (int r = 0; r < 4; ++r) {
        atomicAdd(&Ob[(size_t)(r0 + r) * ost + c0],           acc00[r]);
        atomicAdd(&Ob[(size_t)(r0 + r) * ost + 16 + c0],      acc01[r]);
        atomicAdd(&Ob[(size_t)(r0 + r + 16) * ost + c0],      acc10[r]);
        atomicAdd(&Ob[(size_t)(r0 + r + 16) * ost + 16 + c0], acc11[r]);
    }
}

// ---------------------------------------------------------------------------
// Conv epilogue: x_t = xtacc + up_l_b (writes bf16 copy), causal conv K=4,
// SiLU -> x_c (f32 + bf16)
// ---------------------------------------------------------------------------
__global__ __launch_bounds__(256) void conv_kernel(
    const float* __restrict__ xtacc, const float* __restrict__ ulb,
    const float* __restrict__ cw, const float* __restrict__ cb,
    bf16* __restrict__ xt_bf, float* __restrict__ xc, bf16* __restrict__ xc_bf)
{
    const int idx = blockIdx.x * 256 + threadIdx.x;
    const int b = idx >> 11, i = idx & 2047;
    const float* row = xtacc + (size_t)b * P;
    const float x0 = row[i] + ulb[i];
    xt_bf[idx] = __float2bfloat16(x0);
    float acc = cb[0] + cw[3] * x0;
    if (i >= 1) acc = fmaf(cw[2], row[i - 1] + ulb[i - 1], acc);
    if (i >= 2) acc = fmaf(cw[1], row[i - 2] + ulb[i - 2], acc);
    if (i >= 3) acc = fmaf(cw[0], row[i - 3] + ulb[i - 3], acc);
    const float sv = acc / (1.f + expf(-acc));
    xc[idx] = sv;
    xc_bf[idx] = __float2bfloat16(sv);
}

// ---------------------------------------------------------------------------
// i_t, f_t (f32 dot products, one block per (b,h))
// ---------------------------------------------------------------------------
__global__ __launch_bounds__(256) void if_kernel(
    const float* __restrict__ xc,
    const float* __restrict__ Wi, const float* __restrict__ Wib,
    const float* __restrict__ Wf, const float* __restrict__ Wfb,
    float* __restrict__ it, float* __restrict__ ft)
{
    const int blk = blockIdx.x;
    const int b = blk >> 3, h = blk & 7;
    const int tid = threadIdx.x;
    const int lane = tid & 63, wv = tid >> 6;
    const float* x = xc + (size_t)b * P;
    const float* wi = Wi + (size_t)h * P;
    const float* wf = Wf + (size_t)h * P;
    float pi = 0.f, pf = 0.f;
    for (int p = tid; p < P; p += 256) {
        const float xv = x[p];
        pi = fmaf(xv, wi[p], pi);
        pf = fmaf(xv, wf[p], pf);
    }
    __shared__ float red[8];
#pragma unroll
    for (int off = 32; off; off >>= 1) {
        pi += __shfl_down(pi, off, 64);
        pf += __shfl_down(pf, off, 64);
    }
    if (lane == 0) { red[wv] = pi; red[4 + wv] = pf; }
    __syncthreads();
    if (tid == 0) {
        it[blk] = red[0] + red[1] + red[2] + red[3] + Wib[h];
        ft[blk] = red[4] + red[5] + red[6] + red[7] + Wfb[h];
    }
}

// ---------------------------------------------------------------------------
// Fused gate kernel: biases folded in; writes c_t, n_t, m_t and y (bf16)
// ---------------------------------------------------------------------------
__global__ __launch_bounds__(256) void gate_kernel(
    const float* __restrict__ c_tm1, const float* __restrict__ n_tm1,
    const float* __restrict__ m_tm1, const float* __restrict__ it_a,
    const float* __restrict__ ft_a,
    const float* __restrict__ qacc, const float* __restrict__ kacc,
    const float* __restrict__ vacc, const float* __restrict__ oacc,
    const float* __restrict__ sacc, const float* __restrict__ racc,
    const float* __restrict__ qb, const float* __restrict__ kb,
    const float* __restrict__ vb, const float* __restrict__ ob,
    const float* __restrict__ rb,
    const float* __restrict__ gn_w, const float* __restrict__ gn_b,
    float* __restrict__ c_out, float* __restrict__ n_out,
    float* __restrict__ m_out, bf16* __restrict__ y)
{
    const int blk = blockIdx.x;          // b*H + h
    const int b = blk >> 3, h = blk & 7;
    const int tid = threadIdx.x;
    const int lane = tid & 63, wv = tid >> 6;
    const float kscale = 0.08838834764831845f;  // 1/sqrt(128)

    __shared__ float sk_[128], sq_[128], sv_[128], snum[128];
    __shared__ float red[8];

    const float it = it_a[blk], ft = ft_a[blk], mp = m_tm1[blk];
    const float mt = fmaxf(ft + mp, it);
    const float ig = expf(it - mt);
    const float fg = expf(ft - mt + mp);
    if (tid == 0) m_out[blk] = mt;

    const int col0 = h * HD;
    const int hid_off = b * HID + col0;
    float den_p = 0.f;
    if (tid < 128) {
        const int col = col0 + tid;
        const float kd = (kacc[hid_off + tid] + kb[col]) * kscale;
        const float qd = qacc[hid_off + tid] + qb[col];
        sk_[tid] = kd; sq_[tid] = qd;
        sv_[tid] = vacc[hid_off + tid] + vb[col];
        const float nn = fg * n_tm1[(size_t)blk * HD + tid] + ig * kd;
        n_out[(size_t)blk * HD + tid] = nn;
        den_p = nn * qd;
    }
    __syncthreads();
#pragma unroll
    for (int off = 32; off; off >>= 1) den_p += __shfl_down(den_p, off, 64);
    if (lane == 0) red[wv] = den_p;
    __syncthreads();
    const float den = fmaxf(red[0] + red[1] + red[2] + red[3], 1.0f);

    const float k0 = sk_[2 * lane], k1 = sk_[2 * lane + 1];
    const float q0 = sq_[2 * lane], q1 = sq_[2 * lane + 1];
    const size_t cbase = (size_t)blk * (HD * HD);
#pragma unroll 4
    for (int r = 0; r < 32; ++r) {
        const int d = r * 4 + wv;
        const float2 c2 = *(const float2*)(c_tm1 + cbase + d * HD + 2 * lane);
        const float a = ig * sv_[d];
        const float c0v = fmaf(fg, c2.x, a * k0);
        const float c1v = fmaf(fg, c2.y, a * k1);
        float2 st; st.x = c0v; st.y = c1v;
        *(float2*)(c_out + cbase + d * HD + 2 * lane) = st;
        float psum = c0v * q0 + c1v * q1;
#pragma unroll
        for (int off = 32; off; off >>= 1) psum += __shfl_down(psum, off, 64);
        if (lane == 0) snum[d] = psum;
    }
    __syncthreads();

    float hval = 0.f, s1 = 0.f, s2 = 0.f;
    if (tid < 128) {
        const int col = col0 + tid;
        const float ot = 1.f / (1.f + expf(-(oacc[hid_off + tid] + ob[col])));
        hval = ot * snum[tid] / den;
        s1 = hval; s2 = hval * hval;
    }
#pragma unroll
    for (int off = 32; off; off >>= 1) {
        s1 += __shfl_down(s1, off, 64);
        s2 += __shfl_down(s2, off, 64);
    }
    if (lane == 0) { red[wv] = s1; red[4 + wv] = s2; }
    __syncthreads();
    const float mu = (red[0] + red[1] + red[2] + red[3]) * (1.f / HD);
    const float ms = (red[4] + red[5] + red[6] + red[7]) * (1.f / HD);
    const float var = ms - mu * mu;
    if (tid < 128) {
        const int col = col0 + tid;
        const float hn = (hval - mu) * rsqrtf(var + EPS) * gn_w[col] + gn_b[col];
        const float sr = racc[hid_off + tid] + rb[col];
        const float silu_r = sr / (1.f + expf(-sr));
        y[hid_off + tid] = __float2bfloat16((hn + sacc[hid_off + tid]) * silu_r);
    }
}

// ---------------------------------------------------------------------------
// Final epilogue: out = dacc + down_b + seq
// ---------------------------------------------------------------------------
__global__ __launch_bounds__(256) void e3_kernel(
    const float* __restrict__ dacc, const float* __restrict__ db,
    const float* __restrict__ seq, float* __restrict__ out)
{
    const int i = blockIdx.x * 256 + threadIdx.x;   // float4 chunks, 65536 total
    const float4 d = ((const float4*)dacc)[i];
    const float4 s = ((const float4*)seq)[i];
    const float4 bb = ((const float4*)db)[i & 255];
    float4 o;
    o.x = d.x + s.x + bb.x; o.y = d.y + s.y + bb.y;
    o.z = d.z + s.z + bb.z; o.w = d.w + s.w + bb.w;
    ((float4*)out)[i] = o;
}

// ---------------------------------------------------------------------------
extern "C" void kernel_launch(void* const* d_in, const int* in_sizes, int n_in,
                              void* d_out, int out_size, void* d_ws, size_t ws_size,
                              hipStream_t stream) {
    const float* seq    = (const float*)d_in[0];
    const float* c_tm1  = (const float*)d_in[1];
    const float* n_tm1  = (const float*)d_in[2];
    const float* m_tm1  = (const float*)d_in[3];
    const float* ln_w   = (const float*)d_in[4];
    const float* ln_b   = (const float*)d_in[5];
    const float* gn_w   = (const float*)d_in[6];
    const float* gn_b   = (const float*)d_in[7];
    const float* up_l_w = (const float*)d_in[8];
    const float* up_l_b = (const float*)d_in[9];
    const float* up_r_w = (const float*)d_in[10];
    const float* up_r_b = (const float*)d_in[11];
    const float* down_w = (const float*)d_in[12];
    const float* down_b = (const float*)d_in[13];
    const float* Wi_w   = (const float*)d_in[14];
    const float* Wi_b   = (const float*)d_in[15];
    const float* Wf_w   = (const float*)d_in[16];
    const float* Wf_b   = (const float*)d_in[17];
    const float* Wo_w   = (const float*)d_in[18];
    const float* Wo_b   = (const float*)d_in[19];
    const float* Wq_w   = (const float*)d_in[20];
    const float* Wq_b   = (const float*)d_in[21];
    const float* Wk_w   = (const float*)d_in[22];
    const float* Wk_b   = (const float*)d_in[23];
    const float* Wv_w   = (const float*)d_in[24];
    const float* Wv_b   = (const float*)d_in[25];
    const float* conv_w = (const float*)d_in[26];
    const float* conv_b = (const float*)d_in[27];
    const float* skip_w = (const float*)d_in[28];

    // --- workspace (f32 accumulators must be zeroed; ~12.1 MB total) ---
    float* ws = (float*)d_ws;
    float* xtacc = ws;                    // 524288
    float* racc  = ws + 524288;           // 262144
    float* qacc  = ws + 786432;
    float* kacc  = ws + 1048576;
    float* vacc  = ws + 1310720;
    float* oacc  = ws + 1572864;
    float* sacc  = ws + 1835008;
    float* dacc  = ws + 2097152;          // ends 2359296 (zero region)
    float* itb   = ws + 2359296;          // 2048
    float* ftb   = ws + 2361344;          // 2048
    bf16* yb_bf   = (bf16*)(ws + 2363392);   // 262144 bf16
    bf16* down_bf = (bf16*)(ws + 2494464);   // 1048576 bf16, ends at float 3018752

    // --- outputs; c_t region doubles as scratch until gate_kernel runs ---
    float* out0  = (float*)d_out;
    float* c_out = out0 + 262144;
    float* n_out = out0 + 33816576;
    float* m_out = out0 + 34078720;

    bf16* wbuf   = (bf16*)c_out;          // 128 MB of pre-gate scratch
    bf16* upl_bf = wbuf;                  // 2097152
    bf16* upr_bf = wbuf + 2097152;        // 1048576
    bf16* wq_bf  = wbuf + 3145728;        // 2097152
    bf16* wk_bf  = wbuf + 5242880;
    bf16* wv_bf  = wbuf + 7340032;
    bf16* wo_bf  = wbuf + 9437184;
    bf16* wsk_bf = wbuf + 11534336;       // ends 13631488
    bf16* xn_bf  = wbuf + 13631488;       // 262144
    bf16* xt_bf  = wbuf + 13893632;       // 524288
    bf16* xc_bf  = wbuf + 14417920;       // 524288
    float* xc_f  = (float*)(wbuf + 14942208);  // 524288 f32

    // zero the atomic accumulators (2359296 floats = 589824 float4)
    zero_kernel<<<2304, 256, 0, stream>>>(ws);

    CvtSegs cv;
    cv.src[0] = up_l_w; cv.dst[0] = upl_bf;
    cv.src[1] = up_r_w; cv.dst[1] = upr_bf;
    cv.src[2] = Wq_w;   cv.dst[2] = wq_bf;
    cv.src[3] = Wk_w;   cv.dst[3] = wk_bf;
    cv.src[4] = Wv_w;   cv.dst[4] = wv_bf;
    cv.src[5] = Wo_w;   cv.dst[5] = wo_bf;
    cv.src[6] = skip_w; cv.dst[6] = wsk_bf;
    cv.src[7] = down_w; cv.dst[7] = down_bf;
    convert_kernel<<<14336, 256, 0, stream>>>(cv);

    ln_kernel<<<B, 256, 0, stream>>>(seq, ln_w, ln_b, xn_bf);

    // GEMM1: x_n @ {up_l, up_r}^T   (K=1024, N-segments of 1024)
    Segs g1{};
    g1.A[0] = xn_bf; g1.W[0] = upl_bf;               g1.O[0] = xtacc;        g1.ostride[0] = P;
    g1.A[1] = xn_bf; g1.W[1] = upl_bf + 1024 * 1024; g1.O[1] = xtacc + 1024; g1.ostride[1] = P;
    g1.A[2] = xn_bf; g1.W[2] = upr_bf;               g1.O[2] = racc;         g1.ostride[2] = HID;
    gemm_bf16_sk<<<dim3(48, 4, 4), 256, 0, stream>>>(g1, 1024, 256);

    conv_kernel<<<(B * P) / 256, 256, 0, stream>>>(
        xtacc, up_l_b, conv_w, conv_b, xt_bf, xc_f, xc_bf);

    // GEMM2: {q,k,skip} from x_c; {v,o} from x_t  (K=2048)
    Segs g2{};
    g2.A[0] = xc_bf; g2.W[0] = wq_bf;  g2.O[0] = qacc; g2.ostride[0] = HID;
    g2.A[1] = xc_bf; g2.W[1] = wk_bf;  g2.O[1] = kacc; g2.ostride[1] = HID;
    g2.A[2] = xt_bf; g2.W[2] = wv_bf;  g2.O[2] = vacc; g2.ostride[2] = HID;
    g2.A[3] = xt_bf; g2.W[3] = wo_bf;  g2.O[3] = oacc; g2.ostride[3] = HID;
    g2.A[4] = xc_bf; g2.W[4] = wsk_bf; g2.O[4] = sacc; g2.ostride[4] = HID;
    gemm_bf16_sk<<<dim3(80, 4, 2), 256, 0, stream>>>(g2, 2048, 1024);

    if_kernel<<<B * H, 256, 0, stream>>>(xc_f, Wi_w, Wi_b, Wf_w, Wf_b, itb, ftb);

    gate_kernel<<<B * H, 256, 0, stream>>>(
        c_tm1, n_tm1, m_tm1, itb, ftb,
        qacc, kacc, vacc, oacc, sacc, racc,
        Wq_b, Wk_b, Wv_b, Wo_b, up_r_b, gn_w, gn_b,
        c_out, n_out, m_out, yb_bf);

    // GEMM3: y @ down^T  (K=1024)
    Segs g3{};
    g3.A[0] = yb_bf; g3.W[0] = down_bf; g3.O[0] = dacc; g3.ostride[0] = HID;
    gemm_bf16_sk<<<dim3(16, 4, 4), 256, 0, stream>>>(g3, 1024, 256);

    e3_kernel<<<256, 256, 0, stream>>>(dacc, down_b, seq, out0);
}